// Round 14
// baseline (444.078 us; speedup 1.0000x reference)
//
#include <hip/hip_runtime.h>
#include <hip/hip_bf16.h>

#define N_NODES 50000
#define N_EDGES 800000
#define N_GRAPHS 64
#define LSTR 136

typedef __attribute__((ext_vector_type(4))) short s4v;
typedef __attribute__((ext_vector_type(8))) short s8v;
typedef __attribute__((ext_vector_type(16))) float f16v;

struct HL { short hi, lo; };

__device__ inline HL bsplit(float f) {
    HL r;
    unsigned u = __float_as_uint(f);
    unsigned rh = (u + 0x7FFFu + ((u >> 16) & 1u)) >> 16;
    r.hi = (short)rh;
    float fh = __uint_as_float(rh << 16);
    float fl = f - fh;
    unsigned u2 = __float_as_uint(fl);
    unsigned rl = (u2 + 0x7FFFu + ((u2 >> 16) & 1u)) >> 16;
    r.lo = (short)rl;
    return r;
}

__device__ inline unsigned short f2bf(float f) {
    unsigned u = __float_as_uint(f);
    return (unsigned short)((u + 0x7FFFu + ((u >> 16) & 1u)) >> 16);
}

__device__ inline float bflo(unsigned u) { return __uint_as_float(u << 16); }
__device__ inline float bfhi(unsigned u) { return __uint_as_float(u & 0xFFFF0000u); }

// ---------------- degree / CSR ----------------

__global__ void k_hist(const int* __restrict__ ei, int* __restrict__ cnt,
                       int* __restrict__ rank, int E) {
    int e = blockIdx.x * 256 + threadIdx.x;
    if (e < E) rank[e] = atomicAdd(&cnt[ei[E + e]], 1);
}

// scan over PADDED counts (deg rounded up to multiple of 8); dinv from real deg
__global__ __launch_bounds__(512) void k_scan_a(const int* __restrict__ cnt,
                                                int* __restrict__ rowptr,
                                                int* __restrict__ bsum,
                                                float* __restrict__ dinv, int n) {
    __shared__ int s[512];
    int t = threadIdx.x;
    int i = blockIdx.x * 512 + t;
    int v = (i < n) ? cnt[i] : 0;
    if (i < n) dinv[i] = rsqrtf((float)(v + 1));
    int pv = (v + 7) & ~7;
    s[t] = pv;
    __syncthreads();
    for (int d = 1; d < 512; d <<= 1) {
        int x = (t >= d) ? s[t - d] : 0;
        __syncthreads();
        s[t] += x;
        __syncthreads();
    }
    if (i < n) rowptr[i] = s[t] - pv;
    if (t == 511) bsum[blockIdx.x] = s[511];
}

__global__ __launch_bounds__(512) void k_scan_c(int* __restrict__ rowptr,
                                                const int* __restrict__ bsum,
                                                int n, int nb) {
    __shared__ int sb[128];
    int t = threadIdx.x;
    if (t < 128) sb[t] = (t < nb) ? bsum[t] : 0;
    __syncthreads();
    for (int d = 1; d < 128; d <<= 1) {
        int x = 0;
        if (t < 128 && t >= d) x = sb[t - d];
        __syncthreads();
        if (t < 128) sb[t] += x;
        __syncthreads();
    }
    int add = (blockIdx.x > 0) ? sb[blockIdx.x - 1] : 0;
    int i = blockIdx.x * 512 + t;
    if (i < n) rowptr[i] += add;
    if (i == 0) rowptr[n] = sb[nb - 1];
}

__global__ void k_fill_csr(const int* __restrict__ ei, const int* __restrict__ rowptr,
                           const int* __restrict__ rank,
                           unsigned short* __restrict__ colA, int E) {
    int e = blockIdx.x * 256 + threadIdx.x;
    if (e >= E) return;
    colA[rowptr[ei[E + e]] + rank[e]] = (unsigned short)ei[e];
}

// ---- prep: qq (0..63) | wsplit (64..199) | CNT zero + dummy row (200..224) | colA pad fill (225..505)
__global__ __launch_bounds__(512) void k_prep(const float* __restrict__ qe,
                                              const float* __restrict__ fc0w,
                                              const float* __restrict__ fc0b,
                                              const float* __restrict__ fc1w,
                                              const float* __restrict__ fc1b,
                                              const float* __restrict__ W0,
                                              const float* __restrict__ W1,
                                              const float* __restrict__ W2,
                                              const float* __restrict__ fc2w,
                                              short* __restrict__ WH,
                                              short* __restrict__ WL,
                                              int* __restrict__ cntz,
                                              unsigned* __restrict__ Hsd,
                                              unsigned short* __restrict__ colA,
                                              float* __restrict__ qq) {
    int b = blockIdx.x, tid = threadIdx.x;
    if (b >= 225) {                       // colA pad prefill: 1,150,016 ushorts as uint4
        int idx = (b - 225) * 512 + tid;
        if (idx < 143752) {
            uint4 p;
            p.x = p.y = p.z = p.w = 0xC350C350u;   // 50000 | 50000<<16
            ((uint4*)colA)[idx] = p;
        }
        return;
    }
    if (b >= 200) {                       // zero CNT (+ dummy Hs row on b==200)
        int idx = (b - 200) * 512 + tid;
        if (idx < 12504) ((int4*)cntz)[idx] = make_int4(0, 0, 0, 0);
        if (b == 200 && tid < 64) Hsd[(unsigned)N_NODES * 64u + tid] = 0u;
        return;
    }
    if (b >= 64) {                        // weight split: 136 blocks x 512 = 69632 exact
        int i = (b - 64) * 512 + tid;
        float val;
        int dst;
        if (i < 65536) {
            int mat = i >> 14, off = i & 16383;
            int k = off >> 7, n = off & 127;
            const float* src = (mat == 0) ? W0 : (mat == 1) ? W1 : (mat == 2) ? W2 : fc1w;
            val = src[k * 128 + n];
            dst = mat * 16384 + n * 128 + k;
        } else {
            int off = i - 65536;
            int k = off >> 5, n = off & 31;
            val = fc2w[k * 32 + n];
            dst = 65536 + n * 128 + k;
        }
        HL r = bsplit(val);
        WH[dst] = r.hi;
        WL[dst] = r.lo;
        return;
    }
    // question path, graph g = b
    __shared__ float qs[768];
    __shared__ float red[512];
    __shared__ float ql[128];
    const float* fc1bot = fc1w + 128 * 128;
    int g = b;
    for (int i = tid; i < 768; i += 512) qs[i] = qe[g * 768 + i];
    __syncthreads();
    int j = tid & 127, sl = tid >> 7;
    int kb = sl * 192;
    float a0 = 0, a1 = 0, a2 = 0, a3 = 0;
    for (int k = 0; k < 192; k += 4) {
        a0 += qs[kb + k + 0] * fc0w[(kb + k + 0) * 128 + j];
        a1 += qs[kb + k + 1] * fc0w[(kb + k + 1) * 128 + j];
        a2 += qs[kb + k + 2] * fc0w[(kb + k + 2) * 128 + j];
        a3 += qs[kb + k + 3] * fc0w[(kb + k + 3) * 128 + j];
    }
    red[tid] = (a0 + a1) + (a2 + a3);
    __syncthreads();
    if (tid < 128)
        ql[tid] = fmaxf(((red[tid] + red[tid + 128]) + (red[tid + 256] + red[tid + 384]))
                        + fc0b[tid], 0.f);
    __syncthreads();
    kb = sl * 32;
    float b0 = 0, b1 = 0;
    for (int k = 0; k < 32; k += 2) {
        b0 += ql[kb + k + 0] * fc1bot[(kb + k + 0) * 128 + j];
        b1 += ql[kb + k + 1] * fc1bot[(kb + k + 1) * 128 + j];
    }
    red[tid] = b0 + b1;
    __syncthreads();
    if (tid < 128)
        qq[g * 128 + tid] = ((red[tid] + red[tid + 128]) + (red[tid + 256] + red[tid + 384]))
                            + fc1b[tid];
}

// ---------------- feature-sliced CSR gather ----------------
// Slice = 16 dwords (32 features, 64 B/row); 4 phases, phase-major blocks so each
// 3.2 MB slice stays L2-resident per XCD. 16 lanes per row-slice -> one wave-load
// covers 4 edges. 8 nodes per wave, 4 waves per block.
__global__ __launch_bounds__(256) void k_gat(const unsigned* __restrict__ Hs,
                                             const int* __restrict__ rowptr,
                                             const unsigned short* __restrict__ colA,
                                             const float* __restrict__ dinv,
                                             const float* __restrict__ bias,
                                             unsigned* __restrict__ GH,
                                             int n, int NB) {
    const int phase = blockIdx.x / NB;
    const int nb = blockIdx.x - phase * NB;
    const int wv = threadIdx.x >> 6, l = threadIdx.x & 63;
    const int d = l & 15;                       // dword within slice
    const unsigned* base = Hs + phase * 16 + d; // + row*64
    const float2 bb = ((const float2*)bias)[phase * 16 + d];

    for (int i = 0; i < 8; ++i) {
        int node = nb * 32 + wv * 8 + i;
        if (node >= n) return;
        int e0 = __builtin_amdgcn_readfirstlane(rowptr[node]);
        int e1 = __builtin_amdgcn_readfirstlane(rowptr[node + 1]);
        float a0 = 0.f, a1 = 0.f;
        for (int e = e0; e < e1; e += 8) {      // 8 edges: 1 scalar idx load + 2 vec loads
            uint4 cw = *(const uint4*)(colA + e);
            unsigned s0 = (l & 32) ? cw.y : cw.x;
            unsigned i0 = (l & 16) ? (s0 >> 16) : (s0 & 0xFFFFu);
            unsigned s1 = (l & 32) ? cw.w : cw.z;
            unsigned i1 = (l & 16) ? (s1 >> 16) : (s1 & 0xFFFFu);
            unsigned u0 = base[i0 * 64u];
            unsigned u1 = base[i1 * 64u];
            a0 += bflo(u0) + bflo(u1);
            a1 += bfhi(u0) + bfhi(u1);
        }
        a0 += __shfl_down(a0, 32);
        a1 += __shfl_down(a1, 32);
        a0 += __shfl_down(a0, 16);
        a1 += __shfl_down(a1, 16);
        if (l < 16) {                           // lanes 0-15 hold the slice sums
            float di = dinv[node];
            unsigned uh = base[(unsigned)node * 64u];
            float o0 = fmaxf((a0 + bflo(uh)) * di + bb.x, 0.f);
            float o1 = fmaxf((a1 + bfhi(uh)) * di + bb.y, 0.f);
            GH[(unsigned)node * 64u + phase * 16 + d] =
                (unsigned)f2bf(o0) | ((unsigned)f2bf(o1) << 16);
        }
    }
}

// ---------------- 2-term MFMA GEMM: Hs_bf16 = (A@W)*dinv[row] ----------------
// SPLITIN 0: A fp32 -> bf16 on the fly     SPLITIN 1: A = GH bf16
template <int SPLITIN>
__global__ __launch_bounds__(128) void gemm_mf(const float* __restrict__ A32,
                                               const unsigned short* __restrict__ GHin,
                                               const short* __restrict__ WTh,
                                               const short* __restrict__ WTl,
                                               const float* __restrict__ dinv,
                                               unsigned short* __restrict__ oHs,
                                               int nrows) {
    __shared__ short Ah[32 * LSTR];
    const int tid = threadIdx.x;
    const int row0 = blockIdx.x * 32;

    if (SPLITIN == 0) {
        #pragma unroll
        for (int i = 0; i < 8; ++i) {
            int u = i * 128 + tid;
            int r = u >> 5, c4 = u & 31;
            int gr = row0 + r;
            float4 v = make_float4(0.f, 0.f, 0.f, 0.f);
            if (gr < nrows) v = ((const float4*)A32)[(size_t)gr * 32 + c4];
            s4v h4 = {(short)f2bf(v.x), (short)f2bf(v.y), (short)f2bf(v.z), (short)f2bf(v.w)};
            *(s4v*)&Ah[r * LSTR + c4 * 4] = h4;
        }
    } else {
        #pragma unroll
        for (int i = 0; i < 4; ++i) {
            int u = i * 128 + tid;
            int r = u >> 4, j = u & 15;
            int gr = row0 + r;
            s8v h8 = {};
            if (gr < nrows) h8 = *(const s8v*)&GHin[(size_t)gr * 128 + j * 8];
            *(s8v*)&Ah[r * LSTR + j * 8] = h8;
        }
    }
    __syncthreads();

    const int wv = tid >> 6, lane = tid & 63;
    const int m = lane & 31, half = lane >> 5;
    const int c0 = wv * 64 + m;
    f16v acc0 = {0.f}, acc1 = {0.f};
    #pragma unroll
    for (int ks = 0; ks < 8; ++ks) {
        int ko = ks * 16 + half * 8;
        s8v ah  = *(const s8v*)&Ah[m * LSTR + ko];
        s8v bh0 = *(const s8v*)&WTh[(size_t)c0 * 128 + ko];
        s8v bl0 = *(const s8v*)&WTl[(size_t)c0 * 128 + ko];
        s8v bh1 = *(const s8v*)&WTh[(size_t)(c0 + 32) * 128 + ko];
        s8v bl1 = *(const s8v*)&WTl[(size_t)(c0 + 32) * 128 + ko];
        acc0 = __builtin_amdgcn_mfma_f32_32x32x16_bf16(ah, bh0, acc0, 0, 0, 0);
        acc0 = __builtin_amdgcn_mfma_f32_32x32x16_bf16(ah, bl0, acc0, 0, 0, 0);
        acc1 = __builtin_amdgcn_mfma_f32_32x32x16_bf16(ah, bh1, acc1, 0, 0, 0);
        acc1 = __builtin_amdgcn_mfma_f32_32x32x16_bf16(ah, bl1, acc1, 0, 0, 0);
    }

    #pragma unroll
    for (int reg = 0; reg < 16; ++reg) {
        int rl = (reg & 3) + 8 * (reg >> 2) + 4 * half;
        int gr = row0 + rl;
        if (gr >= nrows) continue;
        float sc = dinv[gr];
        oHs[(size_t)gr * 128 + c0]      = f2bf(acc0[reg] * sc);
        oHs[(size_t)gr * 128 + c0 + 32] = f2bf(acc1[reg] * sc);
    }
}

// ---------------- fused fc1+fc2 -> d_out ----------------
__global__ __launch_bounds__(128) void k_fc12(const unsigned short* __restrict__ GHin,
                                              const short* __restrict__ W1h,
                                              const short* __restrict__ W1l,
                                              const short* __restrict__ W2h,
                                              const short* __restrict__ W2l,
                                              const float* __restrict__ qq,
                                              const int* __restrict__ batch,
                                              const float* __restrict__ bias,
                                              float* __restrict__ out, int nrows) {
    __shared__ short Ph[32 * LSTR], Pl[32 * LSTR];
    __shared__ float red[32 * 33];
    const int tid = threadIdx.x;
    const int row0 = blockIdx.x * 32;

    #pragma unroll
    for (int i = 0; i < 4; ++i) {
        int u = i * 128 + tid;
        int r = u >> 4, j = u & 15;
        int gr = row0 + r;
        s8v h8 = {};
        if (gr < nrows) h8 = *(const s8v*)&GHin[(size_t)gr * 128 + j * 8];
        *(s8v*)&Ph[r * LSTR + j * 8] = h8;
    }
    __syncthreads();

    const int wv = tid >> 6, lane = tid & 63;
    const int m = lane & 31, half = lane >> 5;
    const int c0 = wv * 64 + m;
    f16v acc0 = {0.f}, acc1 = {0.f};
    #pragma unroll
    for (int ks = 0; ks < 8; ++ks) {
        int ko = ks * 16 + half * 8;
        s8v ah  = *(const s8v*)&Ph[m * LSTR + ko];
        s8v bh0 = *(const s8v*)&W1h[(size_t)c0 * 128 + ko];
        s8v bl0 = *(const s8v*)&W1l[(size_t)c0 * 128 + ko];
        s8v bh1 = *(const s8v*)&W1h[(size_t)(c0 + 32) * 128 + ko];
        s8v bl1 = *(const s8v*)&W1l[(size_t)(c0 + 32) * 128 + ko];
        acc0 = __builtin_amdgcn_mfma_f32_32x32x16_bf16(ah, bh0, acc0, 0, 0, 0);
        acc0 = __builtin_amdgcn_mfma_f32_32x32x16_bf16(ah, bl0, acc0, 0, 0, 0);
        acc1 = __builtin_amdgcn_mfma_f32_32x32x16_bf16(ah, bh1, acc1, 0, 0, 0);
        acc1 = __builtin_amdgcn_mfma_f32_32x32x16_bf16(ah, bl1, acc1, 0, 0, 0);
    }
    __syncthreads();

    #pragma unroll
    for (int reg = 0; reg < 16; ++reg) {
        int rl = (reg & 3) + 8 * (reg >> 2) + 4 * half;
        int gr = row0 + rl;
        int g = (gr < nrows) ? batch[gr] : 0;
        float q0 = qq[(size_t)g * 128 + c0];
        float q1 = qq[(size_t)g * 128 + c0 + 32];
        float v0 = fmaxf(acc0[reg] + q0, 0.f);
        float v1 = fmaxf(acc1[reg] + q1, 0.f);
        HL p0 = bsplit(v0), p1 = bsplit(v1);
        Ph[rl * LSTR + c0] = p0.hi;
        Pl[rl * LSTR + c0] = p0.lo;
        Ph[rl * LSTR + c0 + 32] = p1.hi;
        Pl[rl * LSTR + c0 + 32] = p1.lo;
    }
    __syncthreads();

    f16v acc2 = {0.f};
    #pragma unroll
    for (int ks = 0; ks < 4; ++ks) {
        int ko = wv * 64 + ks * 16 + half * 8;
        s8v ah = *(const s8v*)&Ph[m * LSTR + ko];
        s8v al = *(const s8v*)&Pl[m * LSTR + ko];
        s8v bh = *(const s8v*)&W2h[(size_t)m * 128 + ko];
        s8v bl = *(const s8v*)&W2l[(size_t)m * 128 + ko];
        acc2 = __builtin_amdgcn_mfma_f32_32x32x16_bf16(ah, bh, acc2, 0, 0, 0);
        acc2 = __builtin_amdgcn_mfma_f32_32x32x16_bf16(ah, bl, acc2, 0, 0, 0);
        acc2 = __builtin_amdgcn_mfma_f32_32x32x16_bf16(al, bh, acc2, 0, 0, 0);
    }
    if (wv == 1) {
        #pragma unroll
        for (int reg = 0; reg < 16; ++reg) {
            int rl = (reg & 3) + 8 * (reg >> 2) + 4 * half;
            red[rl * 33 + m] = acc2[reg];
        }
    }
    __syncthreads();
    if (wv == 0) {
        #pragma unroll
        for (int reg = 0; reg < 16; ++reg) {
            int rl = (reg & 3) + 8 * (reg >> 2) + 4 * half;
            int gr = row0 + rl;
            if (gr < nrows)
                out[(size_t)gr * 32 + m] = acc2[reg] + red[rl * 33 + m] + bias[m];
        }
    }
}

// ---------------- launch ----------------

extern "C" void kernel_launch(void* const* d_in, const int* in_sizes, int n_in,
                              void* d_out, int out_size, void* d_ws, size_t ws_size,
                              hipStream_t stream) {
    const float* x    = (const float*)d_in[0];
    const int*   ei   = (const int*)d_in[1];
    const int*   batch= (const int*)d_in[2];
    const float* qe   = (const float*)d_in[3];
    const float* W0   = (const float*)d_in[4];
    const float* b0   = (const float*)d_in[5];
    const float* W1   = (const float*)d_in[6];
    const float* b1   = (const float*)d_in[7];
    const float* W2   = (const float*)d_in[8];
    const float* b2   = (const float*)d_in[9];
    const float* fc0w = (const float*)d_in[10];
    const float* fc0b = (const float*)d_in[11];
    const float* fc1w = (const float*)d_in[12];
    const float* fc1b = (const float*)d_in[13];
    const float* fc2w = (const float*)d_in[14];
    const float* fc2b = (const float*)d_in[15];
    float* out = (float*)d_out;

    float* WS = (float*)d_ws;
    unsigned short* HS = (unsigned short*)WS;                 // bf16 [50001,128] (+pad row)
    unsigned short* GH = (unsigned short*)(WS + 3200064);     // bf16 [50000,128]
    float* DINV = WS + 6400064;              // [50016]
    float* QQ   = WS + 6450080;              // [8192]
    int*   CNT  = (int*)(WS + 6458272);      // [50016]
    int*   ROWPTR = (int*)(WS + 6508288);    // [50016]
    int*   RANK = (int*)(WS + 6558304);      // [800000]
    unsigned short* COL = (unsigned short*)(WS + 7358304);    // [1150016] ushort
    int*   BSUM = (int*)(WS + 7933312);      // [128]
    short* WTH  = (short*)(WS + 7933440);    // [69632]
    short* WTL  = WTH + 69632;               // [69632]

    const int N = N_NODES, E = N_EDGES;
    const int eb = (E + 255) / 256;
    const int sb = (N + 511) / 512;          // 98
    const int gg = (N + 31) / 32;            // 1563
    const int NB = (N + 31) / 32;            // gather node-blocks per phase

    // ---- prep (qq + wsplit + CNT zero + dummy row + colA pad prefill) ----
    k_prep<<<506, 512, 0, stream>>>(qe, fc0w, fc0b, fc1w, fc1b, W0, W1, W2, fc2w,
                                    WTH, WTL, CNT, (unsigned*)HS, COL, QQ);
    // ---- CSR build (padded, atomic-free fill) ----
    k_hist<<<eb, 256, 0, stream>>>(ei, CNT, RANK, E);
    k_scan_a<<<sb, 512, 0, stream>>>(CNT, ROWPTR, BSUM, DINV, N);
    k_scan_c<<<sb, 512, 0, stream>>>(ROWPTR, BSUM, N, sb);
    k_fill_csr<<<eb, 256, 0, stream>>>(ei, ROWPTR, RANK, COL, E);

    // ---- layer 1 ----
    gemm_mf<0><<<gg, 128, 0, stream>>>(x, nullptr, WTH, WTL, DINV, HS, N);
    k_gat<<<4 * NB, 256, 0, stream>>>((const unsigned*)HS, ROWPTR, COL, DINV, b0,
                                      (unsigned*)GH, N, NB);
    // ---- layer 2 ----
    gemm_mf<1><<<gg, 128, 0, stream>>>(nullptr, GH, WTH + 16384, WTL + 16384, DINV, HS, N);
    k_gat<<<4 * NB, 256, 0, stream>>>((const unsigned*)HS, ROWPTR, COL, DINV, b1,
                                      (unsigned*)GH, N, NB);
    // ---- layer 3 ----
    gemm_mf<1><<<gg, 128, 0, stream>>>(nullptr, GH, WTH + 32768, WTL + 32768, DINV, HS, N);
    k_gat<<<4 * NB, 256, 0, stream>>>((const unsigned*)HS, ROWPTR, COL, DINV, b2,
                                      (unsigned*)GH, N, NB);

    // ---- fused fc1 + fc2 -> d_out ----
    k_fc12<<<gg, 128, 0, stream>>>(GH, WTH + 49152, WTL + 49152,
                                   WTH + 65536, WTL + 65536,
                                   QQ, batch, fc2b, out, N);
}

// Round 15
// 312.282 us; speedup vs baseline: 1.4220x; 1.4220x over previous
//
#include <hip/hip_runtime.h>
#include <hip/hip_bf16.h>

#define N_NODES 50000
#define N_EDGES 800000
#define N_GRAPHS 64
#define LSTR 136

typedef __attribute__((ext_vector_type(4))) short s4v;
typedef __attribute__((ext_vector_type(8))) short s8v;
typedef __attribute__((ext_vector_type(16))) float f16v;

struct HL { short hi, lo; };

__device__ inline HL bsplit(float f) {
    HL r;
    unsigned u = __float_as_uint(f);
    unsigned rh = (u + 0x7FFFu + ((u >> 16) & 1u)) >> 16;
    r.hi = (short)rh;
    float fh = __uint_as_float(rh << 16);
    float fl = f - fh;
    unsigned u2 = __float_as_uint(fl);
    unsigned rl = (u2 + 0x7FFFu + ((u2 >> 16) & 1u)) >> 16;
    r.lo = (short)rl;
    return r;
}

__device__ inline unsigned short f2bf(float f) {
    unsigned u = __float_as_uint(f);
    return (unsigned short)((u + 0x7FFFu + ((u >> 16) & 1u)) >> 16);
}

__device__ inline float bflo(unsigned u) { return __uint_as_float(u << 16); }
__device__ inline float bfhi(unsigned u) { return __uint_as_float(u & 0xFFFF0000u); }

// one 8-edge group: uniform uint4 index load + 8 gathered dwords
__device__ inline void gat8(const unsigned* __restrict__ Hs,
                            const unsigned short* __restrict__ colA,
                            int e, int l, float& a0, float& a1) {
    uint4 cw = *(const uint4*)(colA + e);
    unsigned u0 = Hs[(cw.x & 0xFFFFu) * 64u + l];
    unsigned u1 = Hs[(cw.x >> 16) * 64u + l];
    unsigned u2 = Hs[(cw.y & 0xFFFFu) * 64u + l];
    unsigned u3 = Hs[(cw.y >> 16) * 64u + l];
    unsigned u4 = Hs[(cw.z & 0xFFFFu) * 64u + l];
    unsigned u5 = Hs[(cw.z >> 16) * 64u + l];
    unsigned u6 = Hs[(cw.w & 0xFFFFu) * 64u + l];
    unsigned u7 = Hs[(cw.w >> 16) * 64u + l];
    a0 += ((bflo(u0) + bflo(u1)) + (bflo(u2) + bflo(u3)))
        + ((bflo(u4) + bflo(u5)) + (bflo(u6) + bflo(u7)));
    a1 += ((bfhi(u0) + bfhi(u1)) + (bfhi(u2) + bfhi(u3)))
        + ((bfhi(u4) + bfhi(u5)) + (bfhi(u6) + bfhi(u7)));
}

// ---------------- CSR scan kernels ----------------

// scan over PADDED counts (deg rounded up to multiple of 8); dinv from real deg
__global__ __launch_bounds__(512) void k_scan_a(const int* __restrict__ cnt,
                                                int* __restrict__ rowptr,
                                                int* __restrict__ bsum,
                                                float* __restrict__ dinv, int n) {
    __shared__ int s[512];
    int t = threadIdx.x;
    int i = blockIdx.x * 512 + t;
    int v = (i < n) ? cnt[i] : 0;
    if (i < n) dinv[i] = rsqrtf((float)(v + 1));
    int pv = (v + 7) & ~7;
    s[t] = pv;
    __syncthreads();
    for (int d = 1; d < 512; d <<= 1) {
        int x = (t >= d) ? s[t - d] : 0;
        __syncthreads();
        s[t] += x;
        __syncthreads();
    }
    if (i < n) rowptr[i] = s[t] - pv;
    if (t == 511) bsum[blockIdx.x] = s[511];
}

__global__ __launch_bounds__(512) void k_scan_c(int* __restrict__ rowptr,
                                                const int* __restrict__ bsum,
                                                int n, int nb) {
    __shared__ int sb[128];
    int t = threadIdx.x;
    if (t < 128) sb[t] = (t < nb) ? bsum[t] : 0;
    __syncthreads();
    for (int d = 1; d < 128; d <<= 1) {
        int x = 0;
        if (t < 128 && t >= d) x = sb[t - d];
        __syncthreads();
        if (t < 128) sb[t] += x;
        __syncthreads();
    }
    int add = (blockIdx.x > 0) ? sb[blockIdx.x - 1] : 0;
    int i = blockIdx.x * 512 + t;
    if (i < n) rowptr[i] += add;
    if (i == 0) rowptr[n] = sb[nb - 1];
}

// ---- prep combo. CNT must be zeroed (memsetAsync) BEFORE this kernel.
// b 0..63: qq | 64..199: wsplit | 200..480: colA pad | 481: dummy Hs row | 482..: hist
__global__ __launch_bounds__(512) void k_prep(const float* __restrict__ qe,
                                              const float* __restrict__ fc0w,
                                              const float* __restrict__ fc0b,
                                              const float* __restrict__ fc1w,
                                              const float* __restrict__ fc1b,
                                              const float* __restrict__ W0,
                                              const float* __restrict__ W1,
                                              const float* __restrict__ W2,
                                              const float* __restrict__ fc2w,
                                              const int* __restrict__ ei,
                                              int* __restrict__ cnt,
                                              int* __restrict__ rank,
                                              short* __restrict__ WH,
                                              short* __restrict__ WL,
                                              unsigned* __restrict__ Hsd,
                                              unsigned short* __restrict__ colA,
                                              float* __restrict__ qq, int E) {
    int b = blockIdx.x, tid = threadIdx.x;
    if (b >= 482) {                       // histogram + rank (CNT pre-zeroed)
        int e = (b - 482) * 512 + tid;
        if (e < E) rank[e] = atomicAdd(&cnt[ei[E + e]], 1);
        return;
    }
    if (b == 481) {                       // dummy Hs row
        if (tid < 64) Hsd[(unsigned)N_NODES * 64u + tid] = 0u;
        return;
    }
    if (b >= 200) {                       // colA pad prefill: 1,150,016 ushorts as uint4
        int idx = (b - 200) * 512 + tid;
        if (idx < 143752) {
            uint4 p;
            p.x = p.y = p.z = p.w = 0xC350C350u;   // 50000 | 50000<<16
            ((uint4*)colA)[idx] = p;
        }
        return;
    }
    if (b >= 64) {                        // weight split: 136 blocks x 512 = 69632 exact
        int i = (b - 64) * 512 + tid;
        float val;
        int dst;
        if (i < 65536) {
            int mat = i >> 14, off = i & 16383;
            int k = off >> 7, n = off & 127;
            const float* src = (mat == 0) ? W0 : (mat == 1) ? W1 : (mat == 2) ? W2 : fc1w;
            val = src[k * 128 + n];
            dst = mat * 16384 + n * 128 + k;
        } else {
            int off = i - 65536;
            int k = off >> 5, n = off & 31;
            val = fc2w[k * 32 + n];
            dst = 65536 + n * 128 + k;
        }
        HL r = bsplit(val);
        WH[dst] = r.hi;
        WL[dst] = r.lo;
        return;
    }
    // question path, graph g = b
    __shared__ float qs[768];
    __shared__ float red[512];
    __shared__ float ql[128];
    const float* fc1bot = fc1w + 128 * 128;
    int g = b;
    for (int i = tid; i < 768; i += 512) qs[i] = qe[g * 768 + i];
    __syncthreads();
    int j = tid & 127, sl = tid >> 7;
    int kb = sl * 192;
    float a0 = 0, a1 = 0, a2 = 0, a3 = 0;
    for (int k = 0; k < 192; k += 4) {
        a0 += qs[kb + k + 0] * fc0w[(kb + k + 0) * 128 + j];
        a1 += qs[kb + k + 1] * fc0w[(kb + k + 1) * 128 + j];
        a2 += qs[kb + k + 2] * fc0w[(kb + k + 2) * 128 + j];
        a3 += qs[kb + k + 3] * fc0w[(kb + k + 3) * 128 + j];
    }
    red[tid] = (a0 + a1) + (a2 + a3);
    __syncthreads();
    if (tid < 128)
        ql[tid] = fmaxf(((red[tid] + red[tid + 128]) + (red[tid + 256] + red[tid + 384]))
                        + fc0b[tid], 0.f);
    __syncthreads();
    kb = sl * 32;
    float b0 = 0, b1 = 0;
    for (int k = 0; k < 32; k += 2) {
        b0 += ql[kb + k + 0] * fc1bot[(kb + k + 0) * 128 + j];
        b1 += ql[kb + k + 1] * fc1bot[(kb + k + 1) * 128 + j];
    }
    red[tid] = b0 + b1;
    __syncthreads();
    if (tid < 128)
        qq[g * 128 + tid] = ((red[tid] + red[tid + 128]) + (red[tid + 256] + red[tid + 384]))
                            + fc1b[tid];
}

// ---------------- merged layer-1 GEMM + CSR fill ----------------
// b < GG: Hs_bf16 = (x@W0)*dinv for rows b*32..   (128 thr, MFMA)
// b >= GG: atomic-free CSR fill, e = (b-GG)*128+tid
__global__ __launch_bounds__(128) void k_fg(const float* __restrict__ A32,
                                            const short* __restrict__ WTh,
                                            const short* __restrict__ WTl,
                                            const float* __restrict__ dinv,
                                            unsigned short* __restrict__ oHs,
                                            const int* __restrict__ ei,
                                            const int* __restrict__ rowptr,
                                            const int* __restrict__ rank,
                                            unsigned short* __restrict__ colA,
                                            int nrows, int E, int GG) {
    const int tid = threadIdx.x;
    if (blockIdx.x >= GG) {                     // CSR fill part
        int e = (blockIdx.x - GG) * 128 + tid;
        if (e < E) colA[rowptr[ei[E + e]] + rank[e]] = (unsigned short)ei[e];
        return;
    }
    __shared__ short Ah[32 * LSTR];
    const int row0 = blockIdx.x * 32;

    #pragma unroll
    for (int i = 0; i < 8; ++i) {
        int u = i * 128 + tid;
        int r = u >> 5, c4 = u & 31;
        int gr = row0 + r;
        float4 v = make_float4(0.f, 0.f, 0.f, 0.f);
        if (gr < nrows) v = ((const float4*)A32)[(size_t)gr * 32 + c4];
        s4v h4 = {(short)f2bf(v.x), (short)f2bf(v.y), (short)f2bf(v.z), (short)f2bf(v.w)};
        *(s4v*)&Ah[r * LSTR + c4 * 4] = h4;
    }
    __syncthreads();

    const int wv = tid >> 6, lane = tid & 63;
    const int m = lane & 31, half = lane >> 5;
    const int c0 = wv * 64 + m;
    f16v acc0 = {0.f}, acc1 = {0.f};
    #pragma unroll
    for (int ks = 0; ks < 8; ++ks) {
        int ko = ks * 16 + half * 8;
        s8v ah  = *(const s8v*)&Ah[m * LSTR + ko];
        s8v bh0 = *(const s8v*)&WTh[(size_t)c0 * 128 + ko];
        s8v bl0 = *(const s8v*)&WTl[(size_t)c0 * 128 + ko];
        s8v bh1 = *(const s8v*)&WTh[(size_t)(c0 + 32) * 128 + ko];
        s8v bl1 = *(const s8v*)&WTl[(size_t)(c0 + 32) * 128 + ko];
        acc0 = __builtin_amdgcn_mfma_f32_32x32x16_bf16(ah, bh0, acc0, 0, 0, 0);
        acc0 = __builtin_amdgcn_mfma_f32_32x32x16_bf16(ah, bl0, acc0, 0, 0, 0);
        acc1 = __builtin_amdgcn_mfma_f32_32x32x16_bf16(ah, bh1, acc1, 0, 0, 0);
        acc1 = __builtin_amdgcn_mfma_f32_32x32x16_bf16(ah, bl1, acc1, 0, 0, 0);
    }

    #pragma unroll
    for (int reg = 0; reg < 16; ++reg) {
        int rl = (reg & 3) + 8 * (reg >> 2) + 4 * half;
        int gr = row0 + rl;
        if (gr >= nrows) continue;
        float sc = dinv[gr];
        oHs[(size_t)gr * 128 + c0]      = f2bf(acc0[reg] * sc);
        oHs[(size_t)gr * 128 + c0 + 32] = f2bf(acc1[reg] * sc);
    }
}

// ---------------- fused gather + GEMM, 512 thr (8 waves), 4 nodes/wave ----------------
// Gather: 16-edge unrolled main loop, two independent accumulator chains (16 loads in
// flight), plus 8-edge remainder. MFMA phase: waves 0-3 (one 32-col block each).
// FC=0: oHs = (G@W)*dinv        FC=1: fc1(relu,+qq) then fc2 -> out
template <int FC>
__global__ __launch_bounds__(512) void k_gg(const unsigned* __restrict__ Hs,
                                            const int* __restrict__ rowptr,
                                            const unsigned short* __restrict__ colA,
                                            const float* __restrict__ dinv,
                                            const float* __restrict__ bias,
                                            const short* __restrict__ WTh,
                                            const short* __restrict__ WTl,
                                            const short* __restrict__ W2h,
                                            const short* __restrict__ W2l,
                                            const float* __restrict__ qq,
                                            const int* __restrict__ batch,
                                            const float* __restrict__ fc2b,
                                            unsigned short* __restrict__ oHs,
                                            float* __restrict__ out,
                                            int n) {
    __shared__ short Ah[32 * LSTR];
    __shared__ short Pl[FC ? 32 * LSTR : 1];
    __shared__ float red[FC ? 3 * 32 * 33 : 1];
    const int tid = threadIdx.x;
    const int row0 = blockIdx.x * 32;
    const int wv = tid >> 6, l = tid & 63;
    const int m = l & 31, half = l >> 5;

    const float2 bb = ((const float2*)bias)[l];
    for (int i = 0; i < 4; ++i) {              // 4 nodes per wave
        int r = wv * 4 + i;
        int node = row0 + r;
        unsigned pack = 0;
        if (node < n) {
            int e0 = __builtin_amdgcn_readfirstlane(rowptr[node]);
            int e1 = __builtin_amdgcn_readfirstlane(rowptr[node + 1]);
            float a0 = 0.f, a1 = 0.f, c0v = 0.f, c1v = 0.f;
            int e = e0;
            for (; e + 16 <= e1; e += 16) {    // 16 loads in flight
                gat8(Hs, colA, e, l, a0, a1);
                gat8(Hs, colA, e + 8, l, c0v, c1v);
            }
            for (; e < e1; e += 8)
                gat8(Hs, colA, e, l, a0, a1);
            a0 += c0v;
            a1 += c1v;
            float di = dinv[node];
            unsigned uh = Hs[(unsigned)node * 64u + l];
            float o0 = fmaxf((a0 + bflo(uh)) * di + bb.x, 0.f);
            float o1 = fmaxf((a1 + bfhi(uh)) * di + bb.y, 0.f);
            pack = (unsigned)f2bf(o0) | ((unsigned)f2bf(o1) << 16);
        }
        ((unsigned*)Ah)[r * 68 + l] = pack;    // LSTR/2 = 68 dwords per row
    }
    __syncthreads();

    const int c0 = wv * 32 + m;                 // waves 0-3: one 32-col block each
    f16v acc = {0.f};
    if (wv < 4) {
        #pragma unroll
        for (int ks = 0; ks < 8; ++ks) {
            int ko = ks * 16 + half * 8;
            s8v ah = *(const s8v*)&Ah[m * LSTR + ko];
            s8v bh = *(const s8v*)&WTh[(size_t)c0 * 128 + ko];
            s8v bl = *(const s8v*)&WTl[(size_t)c0 * 128 + ko];
            acc = __builtin_amdgcn_mfma_f32_32x32x16_bf16(ah, bh, acc, 0, 0, 0);
            acc = __builtin_amdgcn_mfma_f32_32x32x16_bf16(ah, bl, acc, 0, 0, 0);
        }
    }

    if (FC == 0) {
        if (wv < 4) {
            #pragma unroll
            for (int reg = 0; reg < 16; ++reg) {
                int rl = (reg & 3) + 8 * (reg >> 2) + 4 * half;
                int gr = row0 + rl;
                if (gr >= n) continue;
                oHs[(size_t)gr * 128 + c0] = f2bf(acc[reg] * dinv[gr]);
            }
        }
    } else {
        __syncthreads();                        // all waves done reading Ah
        if (wv < 4) {
            #pragma unroll
            for (int reg = 0; reg < 16; ++reg) {  // relu(+qq), split into Ah/Pl planes
                int rl = (reg & 3) + 8 * (reg >> 2) + 4 * half;
                int gr = row0 + rl;
                int g = (gr < n) ? batch[gr] : 0;
                float v = fmaxf(acc[reg] + qq[(size_t)g * 128 + c0], 0.f);
                HL p = bsplit(v);
                Ah[rl * LSTR + c0] = p.hi;
                Pl[rl * LSTR + c0] = p.lo;
            }
        }
        __syncthreads();
        f16v acc2 = {0.f};                      // fc2, split-K across waves 0-3
        if (wv < 4) {
            #pragma unroll
            for (int ks = 0; ks < 2; ++ks) {
                int ko = wv * 32 + ks * 16 + half * 8;
                s8v ah = *(const s8v*)&Ah[m * LSTR + ko];
                s8v al = *(const s8v*)&Pl[m * LSTR + ko];
                s8v bh = *(const s8v*)&W2h[(size_t)m * 128 + ko];
                s8v bl = *(const s8v*)&W2l[(size_t)m * 128 + ko];
                acc2 = __builtin_amdgcn_mfma_f32_32x32x16_bf16(ah, bh, acc2, 0, 0, 0);
                acc2 = __builtin_amdgcn_mfma_f32_32x32x16_bf16(ah, bl, acc2, 0, 0, 0);
                acc2 = __builtin_amdgcn_mfma_f32_32x32x16_bf16(al, bh, acc2, 0, 0, 0);
            }
            if (wv > 0) {
                #pragma unroll
                for (int reg = 0; reg < 16; ++reg) {
                    int rl = (reg & 3) + 8 * (reg >> 2) + 4 * half;
                    red[(wv - 1) * 1056 + rl * 33 + m] = acc2[reg];
                }
            }
        }
        __syncthreads();
        if (wv == 0) {
            #pragma unroll
            for (int reg = 0; reg < 16; ++reg) {
                int rl = (reg & 3) + 8 * (reg >> 2) + 4 * half;
                int gr = row0 + rl;
                if (gr < n)
                    out[(size_t)gr * 32 + m] = acc2[reg]
                        + (red[rl * 33 + m] + red[1056 + rl * 33 + m])
                        + red[2112 + rl * 33 + m] + fc2b[m];
            }
        }
    }
}

// ---------------- launch ----------------

extern "C" void kernel_launch(void* const* d_in, const int* in_sizes, int n_in,
                              void* d_out, int out_size, void* d_ws, size_t ws_size,
                              hipStream_t stream) {
    const float* x    = (const float*)d_in[0];
    const int*   ei   = (const int*)d_in[1];
    const int*   batch= (const int*)d_in[2];
    const float* qe   = (const float*)d_in[3];
    const float* W0   = (const float*)d_in[4];
    const float* b0   = (const float*)d_in[5];
    const float* W1   = (const float*)d_in[6];
    const float* b1   = (const float*)d_in[7];
    const float* W2   = (const float*)d_in[8];
    const float* b2   = (const float*)d_in[9];
    const float* fc0w = (const float*)d_in[10];
    const float* fc0b = (const float*)d_in[11];
    const float* fc1w = (const float*)d_in[12];
    const float* fc1b = (const float*)d_in[13];
    const float* fc2w = (const float*)d_in[14];
    const float* fc2b = (const float*)d_in[15];
    float* out = (float*)d_out;

    float* WS = (float*)d_ws;
    unsigned short* HS  = (unsigned short*)WS;                // bf16 [50001,128]
    unsigned short* HS2 = (unsigned short*)(WS + 3200064);    // bf16 [50001,128]
    float* DINV = WS + 6400128;              // [50016]
    float* QQ   = WS + 6450144;              // [8192]
    int*   CNT  = (int*)(WS + 6458336);      // [50016]
    int*   ROWPTR = (int*)(WS + 6508352);    // [50016]
    int*   RANK = (int*)(WS + 6558368);      // [800000]
    unsigned short* COL = (unsigned short*)(WS + 7358368);    // [1150016] ushort
    int*   BSUM = (int*)(WS + 7933376);      // [128]
    short* WTH  = (short*)(WS + 7933504);    // [69632]
    short* WTL  = WTH + 69632;               // [69632]

    const int N = N_NODES, E = N_EDGES;
    const int sb = (N + 511) / 512;          // 98
    const int gg = (N + 31) / 32;            // 1563
    const int histb = (E + 511) / 512;       // 1563
    const int fillb = (E + 127) / 128;       // 6250

    // ---- CNT zero, then prep (qq + wsplit + colA pad + dummy row + hist) ----
    (void)hipMemsetAsync(CNT, 0, N * sizeof(int), stream);
    k_prep<<<482 + histb, 512, 0, stream>>>(qe, fc0w, fc0b, fc1w, fc1b,
                                            W0, W1, W2, fc2w, ei, CNT, RANK,
                                            WTH, WTL, (unsigned*)HS, COL, QQ, E);
    // ---- scan ----
    k_scan_a<<<sb, 512, 0, stream>>>(CNT, ROWPTR, BSUM, DINV, N);
    k_scan_c<<<sb, 512, 0, stream>>>(ROWPTR, BSUM, N, sb);
    // ---- layer-1 GEMM (x@W0 -> HS) + CSR fill, merged ----
    k_fg<<<gg + fillb, 128, 0, stream>>>(x, WTH, WTL, DINV, HS,
                                         ei, ROWPTR, RANK, COL, N, E, gg);
    // ---- layer 2: gather(HS,b0) + @W1 -> HS2 ----
    k_gg<0><<<gg, 512, 0, stream>>>((const unsigned*)HS, ROWPTR, COL, DINV, b0,
                                    WTH + 16384, WTL + 16384, nullptr, nullptr,
                                    nullptr, nullptr, nullptr, HS2, nullptr, N);
    // ---- layer 3: gather(HS2,b1) + @W2 -> HS ----
    k_gg<0><<<gg, 512, 0, stream>>>((const unsigned*)HS2, ROWPTR, COL, DINV, b1,
                                    WTH + 32768, WTL + 32768, nullptr, nullptr,
                                    nullptr, nullptr, nullptr, HS, nullptr, N);
    // ---- final: gather(HS,b2) + fc1(+qq,relu) + fc2 -> d_out ----
    k_gg<1><<<gg, 512, 0, stream>>>((const unsigned*)HS, ROWPTR, COL, DINV, b2,
                                    WTH + 49152, WTL + 49152, WTH + 65536, WTL + 65536,
                                    QQ, batch, fc2b, nullptr, out, N);
}